// Round 21
// baseline (229.076 us; speedup 1.0000x reference)
//
#include <hip/hip_runtime.h>
#include <hip/hip_fp16.h>
#include <cstdint>
#include <cstddef>

#define NEG 0.2f

typedef _Float16 f16x8 __attribute__((ext_vector_type(8)));
typedef float f32x4 __attribute__((ext_vector_type(4)));

__device__ inline float lrelu(float v) { return v > 0.f ? v : NEG * v; }

// ---- fused: degree count + W1 pre-swizzle (disjoint block ranges) ----------
__global__ void k_pre(const int* __restrict__ ei, int* __restrict__ deg,
                      const float* __restrict__ W1, f16x8* __restrict__ W1s,
                      int E, int ET) {
  int e = blockIdx.x * 256 + threadIdx.x;
  if (e < ET) {
    int d = (e < E) ? ei[E + e] : e - E;
    atomicAdd(&deg[d], 1);
  }
  if (blockIdx.x < 16) {
    int tau = blockIdx.x * 256 + threadIdx.x;  // 0..4095
    int l = tau & 63, ct = (tau >> 6) & 15, ks = tau >> 10;
    int col = ct * 16 + (l & 15);
    f16x8 v;
    #pragma unroll
    for (int j = 0; j < 8; j++) {
      int k = ks * 32 + ((j < 4) ? ((l >> 4) * 4 + j) : (16 + (l >> 4) * 4 + (j - 4)));
      v[j] = (_Float16)W1[k * 256 + col];
    }
    W1s[tau] = v;
  }
}

// ---- fused GEMM1 (MFMA fp16) + att logits + fp16 H + chunk-sum scan --------
__global__ __launch_bounds__(256) void k_gemm1f(const float* __restrict__ X,
                                                const f16x8* __restrict__ W1s,
                                                const float* __restrict__ as1,
                                                const float* __restrict__ ad1,
                                                __half* __restrict__ H16,
                                                float* __restrict__ als,
                                                float* __restrict__ ald,
                                                const int* __restrict__ deg,
                                                int* __restrict__ bsum,
                                                int N, int NB) {
  __shared__ __align__(16) char lds[32768];
  _Float16* A = (_Float16*)lds;
  int t = threadIdx.x;
  int rb = blockIdx.x * 64;
  int l = t & 63, wv = t >> 6;

  #pragma unroll
  for (int i = 0; i < 8; i++) {
    int idx = i * 256 + t;
    int row = idx >> 5, q = idx & 31;
    int gr = rb + row; if (gr >= N) gr = N - 1;
    float4 xv = *(const float4*)(X + (size_t)gr * 128 + q * 4);
    int ks = q >> 3, g = q & 3, hg = (q >> 2) & 1;
    int gran = (ks * 4 + g) ^ (row & 7);
    _Float16* dst = A + row * 128 + gran * 8 + hg * 4;
    dst[0] = (_Float16)xv.x; dst[1] = (_Float16)xv.y;
    dst[2] = (_Float16)xv.z; dst[3] = (_Float16)xv.w;
  }
  __syncthreads();

  f32x4 acc[4][4] = {};
  #pragma unroll
  for (int ks = 0; ks < 4; ks++) {
    f16x8 bfr[4];
    #pragma unroll
    for (int ct = 0; ct < 4; ct++)
      bfr[ct] = W1s[(ks * 16 + wv * 4 + ct) * 64 + l];
    #pragma unroll
    for (int rt = 0; rt < 4; rt++) {
      int row = rt * 16 + (l & 15);
      int gran = (ks * 4 + (l >> 4)) ^ (row & 7);
      f16x8 afr = *(const f16x8*)(A + row * 128 + gran * 8);
      #pragma unroll
      for (int ct = 0; ct < 4; ct++)
        acc[rt][ct] = __builtin_amdgcn_mfma_f32_16x16x32_f16(afr, bfr[ct], acc[rt][ct], 0, 0, 0);
    }
  }

  float asv[4], adv[4];
  #pragma unroll
  for (int ct = 0; ct < 4; ct++) {
    asv[ct] = as1[wv * 64 + ct * 16 + (l & 15)];
    adv[ct] = ad1[wv * 64 + ct * 16 + (l & 15)];
  }
  #pragma unroll
  for (int rt = 0; rt < 4; rt++) {
    #pragma unroll
    for (int j = 0; j < 4; j++) {
      float ps = 0.f, pd = 0.f;
      #pragma unroll
      for (int ct = 0; ct < 4; ct++) {
        ps += acc[rt][ct][j] * asv[ct];
        pd += acc[rt][ct][j] * adv[ct];
      }
      ps += __shfl_xor(ps, 1); ps += __shfl_xor(ps, 2);
      ps += __shfl_xor(ps, 4); ps += __shfl_xor(ps, 8);
      pd += __shfl_xor(pd, 1); pd += __shfl_xor(pd, 2);
      pd += __shfl_xor(pd, 4); pd += __shfl_xor(pd, 8);
      if ((l & 15) == 0) {
        int gr = rb + rt * 16 + (l >> 4) * 4 + j;
        if (gr < N) { als[gr * 4 + wv] = ps; ald[gr * 4 + wv] = pd; }
      }
    }
  }

  __syncthreads();
  _Float16* HL = (_Float16*)lds;
  #pragma unroll
  for (int rt = 0; rt < 4; rt++) {
    #pragma unroll
    for (int j = 0; j < 4; j++) {
      int row = rt * 16 + (l >> 4) * 4 + j;
      #pragma unroll
      for (int ct = 0; ct < 4; ct++) {
        int col = wv * 64 + ct * 16 + (l & 15);
        int g2 = (col >> 3) ^ ((row & 7) << 2);
        HL[row * 256 + g2 * 8 + (col & 7)] = (_Float16)acc[rt][ct][j];
      }
    }
  }
  __syncthreads();
  #pragma unroll
  for (int i = 0; i < 8; i++) {
    int idx = i * 256 + t;
    int row = idx >> 5, g = idx & 31;
    int g2 = g ^ ((row & 7) << 2);
    f32x4 v = *(const f32x4*)(HL + row * 256 + g2 * 8);
    int gr = rb + row;
    if (gr < N) *(f32x4*)((char*)H16 + (size_t)gr * 512 + g * 16) = v;
  }

  // folded k_scan_partial: chunk sums of deg (deg complete: k_pre ran before)
  if (blockIdx.x < (unsigned)NB) {
    __syncthreads();
    int* sd = (int*)lds;
    int base = blockIdx.x * 1024 + t * 4;
    int s = 0;
    #pragma unroll
    for (int j = 0; j < 4; j++) { int i = base + j; s += (i < N) ? deg[i] : 0; }
    sd[t] = s;
    __syncthreads();
    for (int o = 128; o > 0; o >>= 1) {
      if (t < o) sd[t] += sd[t + o];
      __syncthreads();
    }
    if (t == 0) bsum[blockIdx.x] = sd[0];
  }
}

// ---- scan final: per-chunk exclusive scan -> offsets + cursor --------------
__global__ __launch_bounds__(256) void k_scan_final(const int* __restrict__ deg,
                                                    const int* __restrict__ bsum,
                                                    int* __restrict__ offsets,
                                                    int* __restrict__ cursor,
                                                    int N, int NB) {
  __shared__ int sd[256];
  __shared__ int boffs;
  int b = blockIdx.x, t = threadIdx.x;
  if (t == 0) {
    int r = 0;
    for (int i = 0; i < b; i++) r += bsum[i];
    boffs = r;
  }
  int base = b * 1024 + t * 4;
  int v[4]; int s = 0;
  #pragma unroll
  for (int j = 0; j < 4; j++) { int i = base + j; v[j] = (i < N) ? deg[i] : 0; s += v[j]; }
  int my = s;
  sd[t] = s;
  __syncthreads();
  for (int o = 1; o < 256; o <<= 1) {
    int add = (t >= o) ? sd[t - o] : 0;
    __syncthreads();
    sd[t] += add;
    __syncthreads();
  }
  int run = sd[t] - my + boffs;
  #pragma unroll
  for (int j = 0; j < 4; j++) {
    int i = base + j;
    if (i < N) { offsets[i] = run; cursor[i] = run; run += v[j]; }
  }
  if (b == NB - 1 && t == 255) offsets[N] = boffs + sd[255];
}

// ---- CSR fill (src only) ----------------------------------------------------
__global__ void k_fill(const int* __restrict__ ei, int* __restrict__ cursor,
                       int* __restrict__ csr_src, int E, int ET) {
  int e = blockIdx.x * 256 + threadIdx.x;
  if (e >= ET) return;
  int s, d;
  if (e < E) { s = ei[e]; d = ei[E + e]; } else { s = d = e - E; }
  int pos = atomicAdd(&cursor[d], 1);
  csr_src[pos] = s;
}

// ---- agg1: 64 lanes/node (2 edge-halves x 32 lanes), inline p, fp16 out ----
__device__ inline void acc8(float4 v, float p, float* a, float& s) {
  __half2 h0 = __builtin_bit_cast(__half2, v.x);
  __half2 h1 = __builtin_bit_cast(__half2, v.y);
  __half2 h2 = __builtin_bit_cast(__half2, v.z);
  __half2 h3 = __builtin_bit_cast(__half2, v.w);
  float2 f0 = __half22float2(h0), f1 = __half22float2(h1);
  float2 f2 = __half22float2(h2), f3 = __half22float2(h3);
  a[0] += p * f0.x; a[1] += p * f0.y; a[2] += p * f1.x; a[3] += p * f1.y;
  a[4] += p * f2.x; a[5] += p * f2.y; a[6] += p * f3.x; a[7] += p * f3.y;
  s += p;
}

__global__ __launch_bounds__(256) void k_agg1(const int* __restrict__ off,
                                              const int* __restrict__ csr_src,
                                              const float* __restrict__ als1,
                                              const float* __restrict__ ald1,
                                              const float4* __restrict__ H16,
                                              const float* __restrict__ b1,
                                              __half* __restrict__ H2, int N) {
  int t = threadIdx.x;
  int n = blockIdx.x * 4 + (t >> 6);   // one wave per node
  if (n >= N) return;
  int lane = t & 31;        // fp16 channels lane*8 .. +7
  int half = (t >> 5) & 1;  // which edge half
  int g = lane >> 3;        // head
  float aldn = ald1[n * 4 + g];
  int st0 = off[n], en0 = off[n + 1];
  int mid = (st0 + en0 + 1) >> 1;
  int st = half ? mid : st0;
  int en = half ? en0 : mid;
  float a[8] = {0.f, 0.f, 0.f, 0.f, 0.f, 0.f, 0.f, 0.f};
  float s = 0.f;
  int i = st;
  for (; i + 4 <= en; i += 4) {
    int s0 = csr_src[i], s1 = csr_src[i + 1], s2 = csr_src[i + 2], s3 = csr_src[i + 3];
    float p0 = __expf(lrelu(als1[s0 * 4 + g] + aldn));
    float p1 = __expf(lrelu(als1[s1 * 4 + g] + aldn));
    float p2 = __expf(lrelu(als1[s2 * 4 + g] + aldn));
    float p3 = __expf(lrelu(als1[s3 * 4 + g] + aldn));
    float4 v0 = H16[(size_t)s0 * 32 + lane];
    float4 v1 = H16[(size_t)s1 * 32 + lane];
    float4 v2 = H16[(size_t)s2 * 32 + lane];
    float4 v3 = H16[(size_t)s3 * 32 + lane];
    acc8(v0, p0, a, s); acc8(v1, p1, a, s); acc8(v2, p2, a, s); acc8(v3, p3, a, s);
  }
  for (; i < en; i++) {
    int s0 = csr_src[i];
    float p0 = __expf(lrelu(als1[s0 * 4 + g] + aldn));
    float4 v0 = H16[(size_t)s0 * 32 + lane];
    acc8(v0, p0, a, s);
  }
  // combine the two halves (wave-level xor-32)
  #pragma unroll
  for (int j = 0; j < 8; j++) a[j] += __shfl_xor(a[j], 32);
  s += __shfl_xor(s, 32);
  if (half == 0) {
    float inv = 1.f / (s + 1e-16f);
    int c0 = lane * 8;
    float4 bb0 = *(const float4*)(b1 + c0);
    float4 bb1 = *(const float4*)(b1 + c0 + 4);
    f16x8 o;
    o[0] = (_Float16)fmaxf(a[0] * inv + bb0.x, 0.f);
    o[1] = (_Float16)fmaxf(a[1] * inv + bb0.y, 0.f);
    o[2] = (_Float16)fmaxf(a[2] * inv + bb0.z, 0.f);
    o[3] = (_Float16)fmaxf(a[3] * inv + bb0.w, 0.f);
    o[4] = (_Float16)fmaxf(a[4] * inv + bb1.x, 0.f);
    o[5] = (_Float16)fmaxf(a[5] * inv + bb1.y, 0.f);
    o[6] = (_Float16)fmaxf(a[6] * inv + bb1.z, 0.f);
    o[7] = (_Float16)fmaxf(a[7] * inv + bb1.w, 0.f);
    *(f16x8*)((char*)H2 + (size_t)n * 512 + lane * 16) = o;
  }
}

// ------- layer2 GEMM (256->16, fp16 in) + attention-logit dots --------------
__global__ __launch_bounds__(256) void k_gemm2(const __half* __restrict__ H2,
                                               const float* __restrict__ W2,
                                               const float* __restrict__ as2,
                                               const float* __restrict__ ad2,
                                               float* __restrict__ Z,
                                               float* __restrict__ als2,
                                               float* __restrict__ ald2, int N) {
  __shared__ float w2s[4096];  // 256x16
  int t = threadIdx.x;
  for (int i = t; i < 4096; i += 256) w2s[i] = W2[i];
  __syncthreads();
  int n = blockIdx.x * 16 + (t >> 4);
  int c = t & 15;
  if (n >= N) return;
  const f16x8* hp = (const f16x8*)((const char*)H2 + (size_t)n * 512);
  float acc = 0.f;
  #pragma unroll 8
  for (int kb = 0; kb < 32; kb++) {
    f16x8 hv = hp[kb];
    #pragma unroll
    for (int j = 0; j < 8; j++)
      acc += (float)hv[j] * w2s[(kb * 8 + j) * 16 + c];
  }
  Z[(size_t)n * 16 + c] = acc;
  float ps = acc * as2[c], pd = acc * ad2[c];
  #pragma unroll
  for (int o = 8; o > 0; o >>= 1) {
    ps += __shfl_down(ps, o, 16);
    pd += __shfl_down(pd, o, 16);
  }
  if (c == 0) { als2[n] = ps; ald2[n] = pd; }
}

// ---- layer2 agg: 32 lanes/node (2 edge-halves x 16), + log_softmax ---------
__global__ __launch_bounds__(256) void k_agg2x(const int* __restrict__ off,
                                               const int* __restrict__ csr_src,
                                               const float* __restrict__ als2,
                                               const float* __restrict__ ald2,
                                               const float* __restrict__ Z,
                                               const float* __restrict__ b2,
                                               float* __restrict__ out, int N) {
  int t = threadIdx.x;
  int n = blockIdx.x * 8 + (t >> 5);
  if (n >= N) return;
  int c = t & 15;
  int half = (t >> 4) & 1;
  float aldn = ald2[n];
  int st0 = off[n], en0 = off[n + 1];
  int mid = (st0 + en0 + 1) >> 1;
  int st = half ? mid : st0;
  int en = half ? en0 : mid;
  float s = 0.f, acc = 0.f;
  int i = st;
  for (; i + 4 <= en; i += 4) {
    int s0 = csr_src[i], s1 = csr_src[i + 1], s2 = csr_src[i + 2], s3 = csr_src[i + 3];
    float p0 = __expf(lrelu(als2[s0] + aldn));
    float p1 = __expf(lrelu(als2[s1] + aldn));
    float p2 = __expf(lrelu(als2[s2] + aldn));
    float p3 = __expf(lrelu(als2[s3] + aldn));
    float z0 = Z[(size_t)s0 * 16 + c];
    float z1 = Z[(size_t)s1 * 16 + c];
    float z2 = Z[(size_t)s2 * 16 + c];
    float z3 = Z[(size_t)s3 * 16 + c];
    acc += p0 * z0 + p1 * z1 + p2 * z2 + p3 * z3;
    s += p0 + p1 + p2 + p3;
  }
  for (; i < en; i++) {
    int s0 = csr_src[i];
    float p0 = __expf(lrelu(als2[s0] + aldn));
    acc += p0 * Z[(size_t)s0 * 16 + c];
    s += p0;
  }
  acc += __shfl_xor(acc, 16);
  s += __shfl_xor(s, 16);
  if (half == 0) {
    float v = acc / (s + 1e-16f) + b2[c];
    float mx = v;
    #pragma unroll
    for (int o = 8; o > 0; o >>= 1) mx = fmaxf(mx, __shfl_xor(mx, o, 16));
    float ex = __expf(v - mx);
    float sm = ex;
    #pragma unroll
    for (int o = 8; o > 0; o >>= 1) sm += __shfl_xor(sm, o, 16);
    out[(size_t)n * 16 + c] = v - mx - logf(sm);
  }
}

extern "C" void kernel_launch(void* const* d_in, const int* in_sizes, int n_in,
                              void* d_out, int out_size, void* d_ws, size_t ws_size,
                              hipStream_t stream) {
  const float* x   = (const float*)d_in[0];
  const int*   ei  = (const int*)d_in[1];
  const float* W1  = (const float*)d_in[2];
  const float* as1 = (const float*)d_in[3];
  const float* ad1 = (const float*)d_in[4];
  const float* b1  = (const float*)d_in[5];
  const float* W2  = (const float*)d_in[6];
  const float* as2 = (const float*)d_in[7];
  const float* ad2 = (const float*)d_in[8];
  const float* b2  = (const float*)d_in[9];
  float* out = (float*)d_out;

  int N  = in_sizes[0] / 128;   // 50000
  int E  = in_sizes[1] / 2;     // 800000
  int ET = E + N;
  int NB = (N + 1023) / 1024;

  char* w = (char*)d_ws;
  size_t off_b = 0;
  auto alloc = [&](size_t bytes) -> char* {
    size_t start = (off_b + 255) & ~(size_t)255;
    off_b = start + bytes;
    return w + start;
  };
  __half*   h16  = (__half*)alloc((size_t)N * 256 * 2);
  __half*   h2   = (__half*)alloc((size_t)N * 256 * 2);
  f16x8*    w1s  = (f16x8*)alloc((size_t)4096 * 16);
  float*    als1 = (float*)alloc((size_t)N * 4 * 4);
  float*    ald1 = (float*)alloc((size_t)N * 4 * 4);
  int*      deg  = (int*)alloc((size_t)N * 4);
  int*      offs = (int*)alloc((size_t)(N + 1) * 4);
  int*      cur  = (int*)alloc((size_t)N * 4);
  int*      bsum = (int*)alloc((size_t)NB * 4);
  int*      csrs = (int*)alloc((size_t)ET * 4);
  float*    z    = (float*)alloc((size_t)N * 16 * 4);
  float*    als2 = (float*)alloc((size_t)N * 4);
  float*    ald2 = (float*)alloc((size_t)N * 4);

  hipMemsetAsync(deg, 0, (size_t)N * 4, stream);

  k_pre<<<(ET + 255) / 256, 256, 0, stream>>>(ei, deg, W1, w1s, E, ET);
  k_gemm1f<<<(N + 63) / 64, 256, 0, stream>>>(x, w1s, as1, ad1, h16, als1, ald1,
                                              deg, bsum, N, NB);
  k_scan_final<<<NB, 256, 0, stream>>>(deg, bsum, offs, cur, N, NB);
  k_fill<<<(ET + 255) / 256, 256, 0, stream>>>(ei, cur, csrs, E, ET);
  k_agg1<<<(N + 3) / 4, 256, 0, stream>>>(offs, csrs, als1, ald1, (const float4*)h16, b1, h2, N);
  k_gemm2<<<(N + 15) / 16, 256, 0, stream>>>(h2, W2, as2, ad2, z, als2, ald2, N);
  k_agg2x<<<(N + 7) / 8, 256, 0, stream>>>(offs, csrs, als2, ald2, z, b2, out, N);
}

// Round 23
// 221.029 us; speedup vs baseline: 1.0364x; 1.0364x over previous
//
#include <hip/hip_runtime.h>
#include <hip/hip_fp16.h>
#include <cstdint>
#include <cstddef>

#define NEG 0.2f

typedef _Float16 f16x8 __attribute__((ext_vector_type(8)));
typedef float f32x4 __attribute__((ext_vector_type(4)));

__device__ inline float lrelu(float v) { return v > 0.f ? v : NEG * v; }

// ---- fused: degree count + W1 pre-swizzle (disjoint block ranges) ----------
__global__ void k_pre(const int* __restrict__ ei, int* __restrict__ deg,
                      const float* __restrict__ W1, f16x8* __restrict__ W1s,
                      int E, int ET) {
  int e = blockIdx.x * 256 + threadIdx.x;
  if (e < ET) {
    int d = (e < E) ? ei[E + e] : e - E;
    atomicAdd(&deg[d], 1);
  }
  if (blockIdx.x < 16) {
    int tau = blockIdx.x * 256 + threadIdx.x;  // 0..4095
    int l = tau & 63, ct = (tau >> 6) & 15, ks = tau >> 10;
    int col = ct * 16 + (l & 15);
    f16x8 v;
    #pragma unroll
    for (int j = 0; j < 8; j++) {
      int k = ks * 32 + ((j < 4) ? ((l >> 4) * 4 + j) : (16 + (l >> 4) * 4 + (j - 4)));
      v[j] = (_Float16)W1[k * 256 + col];
    }
    W1s[tau] = v;
  }
}

// ---- fused GEMM1 (MFMA fp16) + att logits + fp16 H + chunk-sum scan --------
__global__ __launch_bounds__(256) void k_gemm1f(const float* __restrict__ X,
                                                const f16x8* __restrict__ W1s,
                                                const float* __restrict__ as1,
                                                const float* __restrict__ ad1,
                                                __half* __restrict__ H16,
                                                float* __restrict__ als,
                                                float* __restrict__ ald,
                                                const int* __restrict__ deg,
                                                int* __restrict__ bsum,
                                                int N, int NB) {
  __shared__ __align__(16) char lds[32768];
  _Float16* A = (_Float16*)lds;
  int t = threadIdx.x;
  int rb = blockIdx.x * 64;
  int l = t & 63, wv = t >> 6;

  #pragma unroll
  for (int i = 0; i < 8; i++) {
    int idx = i * 256 + t;
    int row = idx >> 5, q = idx & 31;
    int gr = rb + row; if (gr >= N) gr = N - 1;
    float4 xv = *(const float4*)(X + (size_t)gr * 128 + q * 4);
    int ks = q >> 3, g = q & 3, hg = (q >> 2) & 1;
    int gran = (ks * 4 + g) ^ (row & 7);
    _Float16* dst = A + row * 128 + gran * 8 + hg * 4;
    dst[0] = (_Float16)xv.x; dst[1] = (_Float16)xv.y;
    dst[2] = (_Float16)xv.z; dst[3] = (_Float16)xv.w;
  }
  __syncthreads();

  f32x4 acc[4][4] = {};
  #pragma unroll
  for (int ks = 0; ks < 4; ks++) {
    f16x8 bfr[4];
    #pragma unroll
    for (int ct = 0; ct < 4; ct++)
      bfr[ct] = W1s[(ks * 16 + wv * 4 + ct) * 64 + l];
    #pragma unroll
    for (int rt = 0; rt < 4; rt++) {
      int row = rt * 16 + (l & 15);
      int gran = (ks * 4 + (l >> 4)) ^ (row & 7);
      f16x8 afr = *(const f16x8*)(A + row * 128 + gran * 8);
      #pragma unroll
      for (int ct = 0; ct < 4; ct++)
        acc[rt][ct] = __builtin_amdgcn_mfma_f32_16x16x32_f16(afr, bfr[ct], acc[rt][ct], 0, 0, 0);
    }
  }

  float asv[4], adv[4];
  #pragma unroll
  for (int ct = 0; ct < 4; ct++) {
    asv[ct] = as1[wv * 64 + ct * 16 + (l & 15)];
    adv[ct] = ad1[wv * 64 + ct * 16 + (l & 15)];
  }
  #pragma unroll
  for (int rt = 0; rt < 4; rt++) {
    #pragma unroll
    for (int j = 0; j < 4; j++) {
      float ps = 0.f, pd = 0.f;
      #pragma unroll
      for (int ct = 0; ct < 4; ct++) {
        ps += acc[rt][ct][j] * asv[ct];
        pd += acc[rt][ct][j] * adv[ct];
      }
      ps += __shfl_xor(ps, 1); ps += __shfl_xor(ps, 2);
      ps += __shfl_xor(ps, 4); ps += __shfl_xor(ps, 8);
      pd += __shfl_xor(pd, 1); pd += __shfl_xor(pd, 2);
      pd += __shfl_xor(pd, 4); pd += __shfl_xor(pd, 8);
      if ((l & 15) == 0) {
        int gr = rb + rt * 16 + (l >> 4) * 4 + j;
        if (gr < N) { als[gr * 4 + wv] = ps; ald[gr * 4 + wv] = pd; }
      }
    }
  }

  __syncthreads();
  _Float16* HL = (_Float16*)lds;
  #pragma unroll
  for (int rt = 0; rt < 4; rt++) {
    #pragma unroll
    for (int j = 0; j < 4; j++) {
      int row = rt * 16 + (l >> 4) * 4 + j;
      #pragma unroll
      for (int ct = 0; ct < 4; ct++) {
        int col = wv * 64 + ct * 16 + (l & 15);
        int g2 = (col >> 3) ^ ((row & 7) << 2);
        HL[row * 256 + g2 * 8 + (col & 7)] = (_Float16)acc[rt][ct][j];
      }
    }
  }
  __syncthreads();
  #pragma unroll
  for (int i = 0; i < 8; i++) {
    int idx = i * 256 + t;
    int row = idx >> 5, g = idx & 31;
    int g2 = g ^ ((row & 7) << 2);
    f32x4 v = *(const f32x4*)(HL + row * 256 + g2 * 8);
    int gr = rb + row;
    if (gr < N) *(f32x4*)((char*)H16 + (size_t)gr * 512 + g * 16) = v;
  }

  // folded k_scan_partial: chunk sums of deg (deg complete: k_pre ran before)
  if (blockIdx.x < (unsigned)NB) {
    __syncthreads();
    int* sd = (int*)lds;
    int base = blockIdx.x * 1024 + t * 4;
    int s = 0;
    #pragma unroll
    for (int j = 0; j < 4; j++) { int i = base + j; s += (i < N) ? deg[i] : 0; }
    sd[t] = s;
    __syncthreads();
    for (int o = 128; o > 0; o >>= 1) {
      if (t < o) sd[t] += sd[t + o];
      __syncthreads();
    }
    if (t == 0) bsum[blockIdx.x] = sd[0];
  }
}

// ---- scan final: per-chunk exclusive scan -> offsets + cursor --------------
__global__ __launch_bounds__(256) void k_scan_final(const int* __restrict__ deg,
                                                    const int* __restrict__ bsum,
                                                    int* __restrict__ offsets,
                                                    int* __restrict__ cursor,
                                                    int N, int NB) {
  __shared__ int sd[256];
  __shared__ int boffs;
  int b = blockIdx.x, t = threadIdx.x;
  if (t == 0) {
    int r = 0;
    for (int i = 0; i < b; i++) r += bsum[i];
    boffs = r;
  }
  int base = b * 1024 + t * 4;
  int v[4]; int s = 0;
  #pragma unroll
  for (int j = 0; j < 4; j++) { int i = base + j; v[j] = (i < N) ? deg[i] : 0; s += v[j]; }
  int my = s;
  sd[t] = s;
  __syncthreads();
  for (int o = 1; o < 256; o <<= 1) {
    int add = (t >= o) ? sd[t - o] : 0;
    __syncthreads();
    sd[t] += add;
    __syncthreads();
  }
  int run = sd[t] - my + boffs;
  #pragma unroll
  for (int j = 0; j < 4; j++) {
    int i = base + j;
    if (i < N) { offsets[i] = run; cursor[i] = run; run += v[j]; }
  }
  if (b == NB - 1 && t == 255) offsets[N] = boffs + sd[255];
}

// ---- CSR fill (src only) ----------------------------------------------------
__global__ void k_fill(const int* __restrict__ ei, int* __restrict__ cursor,
                       int* __restrict__ csr_src, int E, int ET) {
  int e = blockIdx.x * 256 + threadIdx.x;
  if (e >= ET) return;
  int s, d;
  if (e < E) { s = ei[e]; d = ei[E + e]; } else { s = d = e - E; }
  int pos = atomicAdd(&cursor[d], 1);
  csr_src[pos] = s;
}

// ---- agg1 + GEMM2 fused, per-wave gemm2, conflict-free k-residue split -----
__device__ inline void acc8(float4 v, float p, float* a, float& s) {
  __half2 h0 = __builtin_bit_cast(__half2, v.x);
  __half2 h1 = __builtin_bit_cast(__half2, v.y);
  __half2 h2 = __builtin_bit_cast(__half2, v.z);
  __half2 h3 = __builtin_bit_cast(__half2, v.w);
  float2 f0 = __half22float2(h0), f1 = __half22float2(h1);
  float2 f2 = __half22float2(h2), f3 = __half22float2(h3);
  a[0] += p * f0.x; a[1] += p * f0.y; a[2] += p * f1.x; a[3] += p * f1.y;
  a[4] += p * f2.x; a[5] += p * f2.y; a[6] += p * f3.x; a[7] += p * f3.y;
  s += p;
}

__global__ __launch_bounds__(256) void k_agg1z(const int* __restrict__ off,
                                               const int* __restrict__ csr_src,
                                               const float* __restrict__ als1,
                                               const float* __restrict__ ald1,
                                               const float4* __restrict__ H16,
                                               const float* __restrict__ b1,
                                               const float* __restrict__ W2,
                                               const float* __restrict__ as2,
                                               const float* __restrict__ ad2,
                                               float* __restrict__ Z,
                                               float* __restrict__ als2,
                                               float* __restrict__ ald2, int N) {
  __shared__ float w2s[4096];                  // W2 [256][16]
  __shared__ __align__(16) float h2L[4][260];  // pad 260
  int t = threadIdx.x;
  for (int i = t; i < 4096; i += 256) w2s[i] = W2[i];
  __syncthreads();   // w2s ready (cheap: waves still in sync here)
  int wv = t >> 6;
  int n = blockIdx.x * 4 + wv;
  if (n >= N) return;  // wave-uniform; no barriers beyond this point
  int l = t & 63;
  int lane = t & 31;
  int half = (t >> 5) & 1;
  int g = lane >> 3;
  float aldn = ald1[n * 4 + g];
  int st0 = off[n], en0 = off[n + 1];
  int mid = (st0 + en0 + 1) >> 1;
  int st = half ? mid : st0;
  int en = half ? en0 : mid;
  float a[8] = {0.f, 0.f, 0.f, 0.f, 0.f, 0.f, 0.f, 0.f};
  float s = 0.f;
  int i = st;
  for (; i + 4 <= en; i += 4) {
    int s0 = csr_src[i], s1 = csr_src[i + 1], s2 = csr_src[i + 2], s3 = csr_src[i + 3];
    float p0 = __expf(lrelu(als1[s0 * 4 + g] + aldn));
    float p1 = __expf(lrelu(als1[s1 * 4 + g] + aldn));
    float p2 = __expf(lrelu(als1[s2 * 4 + g] + aldn));
    float p3 = __expf(lrelu(als1[s3 * 4 + g] + aldn));
    float4 v0 = H16[(size_t)s0 * 32 + lane];
    float4 v1 = H16[(size_t)s1 * 32 + lane];
    float4 v2 = H16[(size_t)s2 * 32 + lane];
    float4 v3 = H16[(size_t)s3 * 32 + lane];
    acc8(v0, p0, a, s); acc8(v1, p1, a, s); acc8(v2, p2, a, s); acc8(v3, p3, a, s);
  }
  for (; i < en; i++) {
    int s0 = csr_src[i];
    float p0 = __expf(lrelu(als1[s0 * 4 + g] + aldn));
    float4 v0 = H16[(size_t)s0 * 32 + lane];
    acc8(v0, p0, a, s);
  }
  #pragma unroll
  for (int j = 0; j < 8; j++) a[j] += __shfl_xor(a[j], 32);
  s += __shfl_xor(s, 32);
  if (half == 0) {
    float inv = 1.f / (s + 1e-16f);
    int c0 = lane * 8;
    #pragma unroll
    for (int j = 0; j < 8; j++)
      h2L[wv][c0 + j] = fmaxf(a[j] * inv + b1[c0 + j], 0.f);
  }
  // wave-internal ordering: LDS writes above complete before reads below
  asm volatile("s_waitcnt lgkmcnt(0)" ::: "memory");
  __builtin_amdgcn_wave_barrier();
  // per-wave gemm2, k-residue split: quarter q handles k = 4*kk + q.
  // w2s bank = (16q + c) mod 32 -> 2-way only (free); h2L read is broadcast.
  int c = l & 15, q = l >> 4;
  int base = 16 * q + c;
  float accz = 0.f;
  #pragma unroll 16
  for (int kk = 0; kk < 64; kk++) {
    accz += h2L[wv][4 * kk + q] * w2s[64 * kk + base];
  }
  accz += __shfl_xor(accz, 16);
  accz += __shfl_xor(accz, 32);
  if (l < 16) {
    Z[(size_t)n * 16 + c] = accz;
    float ps = accz * as2[c], pd = accz * ad2[c];
    #pragma unroll
    for (int o = 8; o > 0; o >>= 1) {
      ps += __shfl_down(ps, o, 16);
      pd += __shfl_down(pd, o, 16);
    }
    if (c == 0) { als2[n] = ps; ald2[n] = pd; }
  }
}

// ---- layer2 agg: 32 lanes/node (2 edge-halves x 16), + log_softmax ---------
__global__ __launch_bounds__(256) void k_agg2x(const int* __restrict__ off,
                                               const int* __restrict__ csr_src,
                                               const float* __restrict__ als2,
                                               const float* __restrict__ ald2,
                                               const float* __restrict__ Z,
                                               const float* __restrict__ b2,
                                               float* __restrict__ out, int N) {
  int t = threadIdx.x;
  int n = blockIdx.x * 8 + (t >> 5);
  if (n >= N) return;
  int c = t & 15;
  int half = (t >> 4) & 1;
  float aldn = ald2[n];
  int st0 = off[n], en0 = off[n + 1];
  int mid = (st0 + en0 + 1) >> 1;
  int st = half ? mid : st0;
  int en = half ? en0 : mid;
  float s = 0.f, acc = 0.f;
  int i = st;
  for (; i + 4 <= en; i += 4) {
    int s0 = csr_src[i], s1 = csr_src[i + 1], s2 = csr_src[i + 2], s3 = csr_src[i + 3];
    float p0 = __expf(lrelu(als2[s0] + aldn));
    float p1 = __expf(lrelu(als2[s1] + aldn));
    float p2 = __expf(lrelu(als2[s2] + aldn));
    float p3 = __expf(lrelu(als2[s3] + aldn));
    float z0 = Z[(size_t)s0 * 16 + c];
    float z1 = Z[(size_t)s1 * 16 + c];
    float z2 = Z[(size_t)s2 * 16 + c];
    float z3 = Z[(size_t)s3 * 16 + c];
    acc += p0 * z0 + p1 * z1 + p2 * z2 + p3 * z3;
    s += p0 + p1 + p2 + p3;
  }
  for (; i < en; i++) {
    int s0 = csr_src[i];
    float p0 = __expf(lrelu(als2[s0] + aldn));
    acc += p0 * Z[(size_t)s0 * 16 + c];
    s += p0;
  }
  acc += __shfl_xor(acc, 16);
  s += __shfl_xor(s, 16);
  if (half == 0) {
    float v = acc / (s + 1e-16f) + b2[c];
    float mx = v;
    #pragma unroll
    for (int o = 8; o > 0; o >>= 1) mx = fmaxf(mx, __shfl_xor(mx, o, 16));
    float ex = __expf(v - mx);
    float sm = ex;
    #pragma unroll
    for (int o = 8; o > 0; o >>= 1) sm += __shfl_xor(sm, o, 16);
    out[(size_t)n * 16 + c] = v - mx - logf(sm);
  }
}

extern "C" void kernel_launch(void* const* d_in, const int* in_sizes, int n_in,
                              void* d_out, int out_size, void* d_ws, size_t ws_size,
                              hipStream_t stream) {
  const float* x   = (const float*)d_in[0];
  const int*   ei  = (const int*)d_in[1];
  const float* W1  = (const float*)d_in[2];
  const float* as1 = (const float*)d_in[3];
  const float* ad1 = (const float*)d_in[4];
  const float* b1  = (const float*)d_in[5];
  const float* W2  = (const float*)d_in[6];
  const float* as2 = (const float*)d_in[7];
  const float* ad2 = (const float*)d_in[8];
  const float* b2  = (const float*)d_in[9];
  float* out = (float*)d_out;

  int N  = in_sizes[0] / 128;   // 50000
  int E  = in_sizes[1] / 2;     // 800000
  int ET = E + N;
  int NB = (N + 1023) / 1024;

  char* w = (char*)d_ws;
  size_t off_b = 0;
  auto alloc = [&](size_t bytes) -> char* {
    size_t start = (off_b + 255) & ~(size_t)255;
    off_b = start + bytes;
    return w + start;
  };
  __half*   h16  = (__half*)alloc((size_t)N * 256 * 2);
  f16x8*    w1s  = (f16x8*)alloc((size_t)4096 * 16);
  float*    als1 = (float*)alloc((size_t)N * 4 * 4);
  float*    ald1 = (float*)alloc((size_t)N * 4 * 4);
  int*      deg  = (int*)alloc((size_t)N * 4);
  int*      offs = (int*)alloc((size_t)(N + 1) * 4);
  int*      cur  = (int*)alloc((size_t)N * 4);
  int*      bsum = (int*)alloc((size_t)NB * 4);
  int*      csrs = (int*)alloc((size_t)ET * 4);
  float*    z    = (float*)alloc((size_t)N * 16 * 4);
  float*    als2 = (float*)alloc((size_t)N * 4);
  float*    ald2 = (float*)alloc((size_t)N * 4);

  hipMemsetAsync(deg, 0, (size_t)N * 4, stream);

  k_pre<<<(ET + 255) / 256, 256, 0, stream>>>(ei, deg, W1, w1s, E, ET);
  k_gemm1f<<<(N + 63) / 64, 256, 0, stream>>>(x, w1s, as1, ad1, h16, als1, ald1,
                                              deg, bsum, N, NB);
  k_scan_final<<<NB, 256, 0, stream>>>(deg, bsum, offs, cur, N, NB);
  k_fill<<<(ET + 255) / 256, 256, 0, stream>>>(ei, cur, csrs, E, ET);
  k_agg1z<<<(N + 3) / 4, 256, 0, stream>>>(offs, csrs, als1, ald1, (const float4*)h16,
                                           b1, W2, as2, ad2, z, als2, ald2, N);
  k_agg2x<<<(N + 7) / 8, 256, 0, stream>>>(offs, csrs, als2, ald2, z, b2, out, N);
}